// Round 8
// baseline (388.357 us; speedup 1.0000x reference)
//
#include <hip/hip_runtime.h>
#include <cmath>

#define N_NODES 100000
#define N_EDGES 3200000
#define IN_DIM 256
#define EMB 64
#define BATCH 4096
#define MWAVES 6250        // 100000 rows / 16 per wave (gemm)
#define NBUCK 782          // ceil(100000 / 128) row-buckets
#define BROWS 128          // rows per bucket
#define BSTRIDE 4608       // u64 slots per bucket (mean 4096 + 8 sigma), %8==0
#define EPB 4096           // edges per passA block

typedef unsigned long long u64;
typedef unsigned int u32;
typedef unsigned short u16;
typedef __attribute__((ext_vector_type(8))) short bf16x8;
typedef __attribute__((ext_vector_type(4))) float f32x4;

// ---------------------------------------------------------------------------
// helpers
// ---------------------------------------------------------------------------
__device__ __forceinline__ float wave_sum(float v) {
#pragma unroll
    for (int m = 1; m < 64; m <<= 1) v += __shfl_xor(v, m, 64);
    return v;
}

__device__ __forceinline__ u16 f2bf_rne(float f) {
    u32 u = __float_as_uint(f);
    u32 r = ((u >> 16) & 1u) + 0x7FFFu;
    return (u16)((u + r) >> 16);
}

__device__ __forceinline__ float bf2f(u32 bits16) {
    return __uint_as_float(bits16 << 16);
}

// ---------------------------------------------------------------------------
// 1) xw = feats @ W via MFMA bf16. W staged in LDS fragment-major (32 KB).
//    All 16 A-tile float4 loads hoisted (one latency exposure per wave).
// ---------------------------------------------------------------------------
__global__ __launch_bounds__(256) void mfma_gemm_kernel(const float* __restrict__ feats,
                                                        const float* __restrict__ W,
                                                        u16* __restrict__ xwb) {
    __shared__ u16 wlds[32 * 64 * 8];   // 32 KB
    const int tid = threadIdx.x;
    for (int idx = tid; idx < 32 * 64; idx += 256) {
        const int f = idx >> 6, lane = idx & 63;
        const int kt = f >> 2, nt = f & 3;
        const int k0 = kt * 32 + (lane >> 4) * 8;
        const int n  = nt * 16 + (lane & 15);
        u32 buf[4];
#pragma unroll
        for (int jj = 0; jj < 4; ++jj) {
            u16 lo = f2bf_rne(W[(size_t)(k0 + 2 * jj) * EMB + n]);
            u16 hi = f2bf_rne(W[(size_t)(k0 + 2 * jj + 1) * EMB + n]);
            buf[jj] = (u32)lo | ((u32)hi << 16);
        }
        *(uint4*)&wlds[idx * 8] = *(uint4*)buf;
    }
    __syncthreads();

    const int wave = tid >> 6, lane = tid & 63;
    const int wid = blockIdx.x * 4 + wave;
    if (wid >= MWAVES) return;
    const int row0 = wid * 16;
    const int arow = row0 + (lane & 15);
    const int kbase = (lane >> 4) * 8;
    const float* fr = feats + (size_t)arow * IN_DIM + kbase;

    float4 av[16];
#pragma unroll
    for (int kt = 0; kt < 8; ++kt) {
        av[2 * kt]     = *(const float4*)(fr + kt * 32);
        av[2 * kt + 1] = *(const float4*)(fr + kt * 32 + 4);
    }

    f32x4 acc[4] = {};
    const u16* wl = &wlds[lane * 8];
#pragma unroll
    for (int kt = 0; kt < 8; ++kt) {
        float4 a0 = av[2 * kt], a1 = av[2 * kt + 1];
        u32 ab[4];
        ab[0] = (u32)f2bf_rne(a0.x) | ((u32)f2bf_rne(a0.y) << 16);
        ab[1] = (u32)f2bf_rne(a0.z) | ((u32)f2bf_rne(a0.w) << 16);
        ab[2] = (u32)f2bf_rne(a1.x) | ((u32)f2bf_rne(a1.y) << 16);
        ab[3] = (u32)f2bf_rne(a1.z) | ((u32)f2bf_rne(a1.w) << 16);
        bf16x8 afrag = *(bf16x8*)ab;
#pragma unroll
        for (int nt = 0; nt < 4; ++nt) {
            bf16x8 bfrag = *(const bf16x8*)&wl[(kt * 4 + nt) * 512];
            acc[nt] = __builtin_amdgcn_mfma_f32_16x16x32_bf16(afrag, bfrag, acc[nt], 0, 0, 0);
        }
    }
    const int rb = row0 + (lane >> 4) * 4;
    const int cb = lane & 15;
#pragma unroll
    for (int nt = 0; nt < 4; ++nt)
#pragma unroll
        for (int r = 0; r < 4; ++r)
            xwb[(size_t)(rb + r) * EMB + nt * 16 + cb] = f2bf_rne(acc[nt][r]);
}

// ---------------------------------------------------------------------------
// 2) passA: partition edges into NBUCK 128-row buckets (R6/R7-proven).
//    Entry packs (row:17 | col:17<<17 | val_bf16<<34).
// ---------------------------------------------------------------------------
__global__ __launch_bounds__(256) void passA_kernel(const int* __restrict__ erow,
                                                    const int* __restrict__ ecol,
                                                    const float* __restrict__ eval,
                                                    u32* __restrict__ gcursor,
                                                    u64* __restrict__ sorted) {
    __shared__ u64 stage[EPB];        // 32 KB
    __shared__ u32 hist[1024];
    __shared__ u32 offs[1024];
    __shared__ u32 cursor[1024];
    __shared__ u32 gbase[1024];
    __shared__ u32 partial[256];

    const int tid = threadIdx.x;
    const int e0 = blockIdx.x * EPB;
    const int total = min(EPB, N_EDGES - e0);

    for (int i = tid; i < 1024; i += 256) hist[i] = 0;
    __syncthreads();

    u64 ent[16];
    int eb[16];
#pragma unroll
    for (int j = 0; j < 16; ++j) {
        const int e = e0 + j * 256 + tid;
        if (e < N_EDGES) {
            const int r = erow[e];
            const int c = ecol[e];
            const u16 vb = f2bf_rne(eval[e]);
            ent[j] = (u64)(u32)r | ((u64)(u32)c << 17) | ((u64)vb << 34);
            eb[j] = r >> 7;
            atomicAdd(&hist[eb[j]], 1u);
        } else {
            eb[j] = -1;
        }
    }
    __syncthreads();

    u32 local[4], s = 0;
#pragma unroll
    for (int q = 0; q < 4; ++q) {
        local[q] = s;
        s += hist[4 * tid + q];
    }
    partial[tid] = s;
    __syncthreads();
    for (int off = 1; off < 256; off <<= 1) {
        u32 x = (tid >= off) ? partial[tid - off] : 0;
        __syncthreads();
        partial[tid] += x;
        __syncthreads();
    }
    const u32 base = partial[tid] - s;
#pragma unroll
    for (int q = 0; q < 4; ++q) {
        offs[4 * tid + q] = base + local[q];
        cursor[4 * tid + q] = base + local[q];
    }
    __syncthreads();

#pragma unroll
    for (int j = 0; j < 16; ++j) {
        if (eb[j] >= 0) {
            u32 pos = atomicAdd(&cursor[eb[j]], 1u);
            stage[pos] = ent[j];
        }
    }
    __syncthreads();

    for (int b = tid; b < 1024; b += 256) {
        const u32 cnt = cursor[b] - offs[b];
        gbase[b] = cnt ? atomicAdd(&gcursor[b], cnt) : 0;
    }
    __syncthreads();

    for (int i = tid; i < total; i += 256) {
        const u64 p = stage[i];
        const int b = (int)(p & 0x1FFFFu) >> 7;
        const u32 gpos = gbase[b] + ((u32)i - offs[b]);
        if (gpos < BSTRIDE) sorted[(size_t)b * BSTRIDE + gpos] = p;
    }
}

// ---------------------------------------------------------------------------
// 3) gather: one block per 128-row bucket (782 blocks). Entries read ONCE,
//    coalesced, into registers; LDS row-sort (128 counters); 4 waves sweep
//    32 rows each with wave-uniform LDS reads + 8-wide unrolled xw gathers.
//    emb (bf16) overlays the bucket's own (dead) global region.
// ---------------------------------------------------------------------------
__global__ __launch_bounds__(256) void gather_kernel(const u16* __restrict__ xwb,
                                                     u64* __restrict__ sorted,
                                                     const u32* __restrict__ gcursor,
                                                     float* __restrict__ accumA) {
    __shared__ u64 stage[BSTRIDE];    // 36864 B
    __shared__ u32 rhist[BROWS], roff[BROWS], rcur[BROWS], sc[BROWS];
    __shared__ float part[4];
    const int tid = threadIdx.x, wave = tid >> 6, lane = tid & 63;
    const int b = blockIdx.x;
    u64* gbase = sorted + (size_t)b * BSTRIDE;
    const int cnt = min((int)gcursor[b], BSTRIDE);

    if (tid < BROWS) rhist[tid] = 0;
    __syncthreads();

    // coalesced one-shot read into registers + histogram from registers
    u64 ent[BSTRIDE / 256];           // 18
    int nloc = 0;
    for (int i = tid; i < cnt; i += 256) {
        u64 p = gbase[i];
        ent[nloc++] = p;
        atomicAdd(&rhist[(int)(p & 127u)], 1u);
    }
    __syncthreads();

    // exclusive scan of 128 row counts (Hillis-Steele, threads 0..127)
    if (tid < BROWS) sc[tid] = rhist[tid];
    __syncthreads();
    for (int off = 1; off < BROWS; off <<= 1) {
        u32 x = (tid < BROWS && tid >= off) ? sc[tid - off] : 0;
        __syncthreads();
        if (tid < BROWS) sc[tid] += x;
        __syncthreads();
    }
    if (tid < BROWS) {
        roff[tid] = sc[tid] - rhist[tid];
        rcur[tid] = sc[tid] - rhist[tid];
    }
    __syncthreads();

    // scatter from registers into row-grouped LDS stage
    for (int j = 0; j < nloc; ++j) {
        const u64 p = ent[j];
        const u32 pos = atomicAdd(&rcur[(int)(p & 127u)], 1u);
        stage[pos] = p;
    }
    __syncthreads();

    // sweep: wave handles rows wave*32 .. wave*32+31
    u16* embp = (u16*)gbase;          // entries dead (staged in LDS)
    float wd = 0.f;
    for (int rr = 0; rr < 32; ++rr) {
        const int r = wave * 32 + rr;
        const int s0 = roff[r], n = rhist[r];
        float acc = 0.f;
        int j = s0;
        const int e2 = s0 + n;
        for (; j + 7 < e2; j += 8) {
            u64 p0 = stage[j],     p1 = stage[j + 1], p2 = stage[j + 2], p3 = stage[j + 3];
            u64 p4 = stage[j + 4], p5 = stage[j + 5], p6 = stage[j + 6], p7 = stage[j + 7];
            float x0 = bf2f(xwb[(size_t)((p0 >> 17) & 0x1FFFFu) * EMB + lane]);
            float x1 = bf2f(xwb[(size_t)((p1 >> 17) & 0x1FFFFu) * EMB + lane]);
            float x2 = bf2f(xwb[(size_t)((p2 >> 17) & 0x1FFFFu) * EMB + lane]);
            float x3 = bf2f(xwb[(size_t)((p3 >> 17) & 0x1FFFFu) * EMB + lane]);
            float x4 = bf2f(xwb[(size_t)((p4 >> 17) & 0x1FFFFu) * EMB + lane]);
            float x5 = bf2f(xwb[(size_t)((p5 >> 17) & 0x1FFFFu) * EMB + lane]);
            float x6 = bf2f(xwb[(size_t)((p6 >> 17) & 0x1FFFFu) * EMB + lane]);
            float x7 = bf2f(xwb[(size_t)((p7 >> 17) & 0x1FFFFu) * EMB + lane]);
            acc += bf2f((u32)(p0 >> 34) & 0xFFFFu) * x0 + bf2f((u32)(p1 >> 34) & 0xFFFFu) * x1;
            acc += bf2f((u32)(p2 >> 34) & 0xFFFFu) * x2 + bf2f((u32)(p3 >> 34) & 0xFFFFu) * x3;
            acc += bf2f((u32)(p4 >> 34) & 0xFFFFu) * x4 + bf2f((u32)(p5 >> 34) & 0xFFFFu) * x5;
            acc += bf2f((u32)(p6 >> 34) & 0xFFFFu) * x6 + bf2f((u32)(p7 >> 34) & 0xFFFFu) * x7;
        }
        for (; j < e2; ++j) {
            u64 p = stage[j];
            acc += bf2f((u32)(p >> 34) & 0xFFFFu) * bf2f(xwb[(size_t)((p >> 17) & 0x1FFFFu) * EMB + lane]);
        }
        float x = tanhf(acc);
        float sq = wave_sum(x * x);
        if (b * BROWS + r < N_NODES)
            embp[r * EMB + lane] = f2bf_rne(x * rsqrtf(fmaxf(sq, 1e-12f)));
        wd += sq / fmaxf(sq, 1e-12f);   // 0 for empty rows
    }
    if (lane == 0) part[wave] = wd;
    __syncthreads();
    if (tid == 0)
        unsafeAtomicAdd(&accumA[b & 255], part[0] + part[1] + part[2] + part[3]);
}

// ---------------------------------------------------------------------------
// 4) BPR: pure emb lookup. One wave per sample.
// ---------------------------------------------------------------------------
__device__ __forceinline__ float emb_ld(const u64* __restrict__ sorted, int row, int lane) {
    const u16* rp = (const u16*)(sorted + (size_t)(row >> 7) * BSTRIDE) + (row & 127) * EMB;
    return bf2f(rp[lane]);
}

__global__ __launch_bounds__(256) void bpr_kernel(const u64* __restrict__ sorted,
                                                  const int* __restrict__ idx1,
                                                  const int* __restrict__ idx2,
                                                  const int* __restrict__ nidx,
                                                  float* __restrict__ accumB) {
    const int wave = threadIdx.x >> 6, lane = threadIdx.x & 63;
    const int i = blockIdx.x * 4 + wave;
    float o1 = emb_ld(sorted, idx1[i], lane);
    float o2 = emb_ld(sorted, idx2[i], lane);
    float on = emb_ld(sorted, nidx[i], lane);
    float yui = wave_sum(o1 * o2);
    float yuj = wave_sum(o1 * on);
    if (lane == 0) {
        float x = yui - yuj;
        float li = (x > 0.f) ? log1pf(expf(-x)) : (-x + log1pf(expf(x)));
        unsafeAtomicAdd(&accumB[i & 255], li);
    }
}

// ---------------------------------------------------------------------------
// 5) finalize
// ---------------------------------------------------------------------------
__global__ __launch_bounds__(64) void finalize_kernel(const float* __restrict__ accumA,
                                                      const float* __restrict__ accumB,
                                                      float* __restrict__ out) {
    const int t = threadIdx.x;
    float wd = 0.f, bp = 0.f;
#pragma unroll
    for (int k = 0; k < 4; ++k) {
        wd += accumA[t + 64 * k];
        bp += accumB[t + 64 * k];
    }
    wd = wave_sum(wd);
    bp = wave_sum(bp);
    if (t == 0) out[0] = (bp + 1e-4f * 0.5f * wd) / (float)BATCH;
}

extern "C" void kernel_launch(void* const* d_in, const int* in_sizes, int n_in,
                              void* d_out, int out_size, void* d_ws, size_t ws_size,
                              hipStream_t stream) {
    const float* feats = (const float*)d_in[0];
    const float* W     = (const float*)d_in[1];
    const int*   erow  = (const int*)d_in[2];
    const int*   ecol  = (const int*)d_in[3];
    const float* eval  = (const float*)d_in[4];
    const int*   idx1  = (const int*)d_in[5];
    const int*   idx2  = (const int*)d_in[6];
    const int*   nidx  = (const int*)d_in[7];
    float* out = (float*)d_out;

    // workspace layout (~41.7 MB)
    u16*   xwb     = (u16*)d_ws;                               // 12.8 MB
    u64*   sorted  = (u64*)(xwb + (size_t)N_NODES * EMB);      // 782*4608*8 = 28.8 MB
    u32*   gcursor = (u32*)(sorted + (size_t)NBUCK * BSTRIDE); // 1024
    float* accumA  = (float*)(gcursor + 1024);                 // 256
    float* accumB  = accumA + 256;                             // 256

    hipMemsetAsync(gcursor, 0, (1024 + 512) * sizeof(u32), stream);

    mfma_gemm_kernel<<<(MWAVES + 3) / 4, 256, 0, stream>>>(feats, W, xwb);
    passA_kernel<<<(N_EDGES + EPB - 1) / EPB, 256, 0, stream>>>(erow, ecol, eval, gcursor, sorted);
    gather_kernel<<<NBUCK, 256, 0, stream>>>(xwb, sorted, gcursor, accumA);
    bpr_kernel<<<BATCH / 4, 256, 0, stream>>>(sorted, idx1, idx2, nidx, accumB);
    finalize_kernel<<<1, 64, 0, stream>>>(accumA, accumB, out);
}

// Round 9
// 345.287 us; speedup vs baseline: 1.1247x; 1.1247x over previous
//
#include <hip/hip_runtime.h>
#include <cmath>

#define N_NODES 100000
#define N_EDGES 3200000
#define IN_DIM 256
#define EMB 64
#define BATCH 4096
#define MWAVES 6250        // 100000 rows / 16 per wave (gemm)
#define NBUCK 782          // ceil(100000 / 128) row-buckets
#define BROWS 128          // rows per bucket
#define BSTRIDE 4608       // u64 slots per bucket (mean 4096 + 8 sigma), %8==0
#define EPB 4096           // edges per passA block

typedef unsigned long long u64;
typedef unsigned int u32;
typedef unsigned short u16;
typedef __attribute__((ext_vector_type(8))) short bf16x8;
typedef __attribute__((ext_vector_type(4))) float f32x4;

// ---------------------------------------------------------------------------
// helpers
// ---------------------------------------------------------------------------
__device__ __forceinline__ float wave_sum(float v) {
#pragma unroll
    for (int m = 1; m < 64; m <<= 1) v += __shfl_xor(v, m, 64);
    return v;
}

__device__ __forceinline__ u16 f2bf_rne(float f) {
    u32 u = __float_as_uint(f);
    u32 r = ((u >> 16) & 1u) + 0x7FFFu;
    return (u16)((u + r) >> 16);
}

__device__ __forceinline__ float bf2f(u32 bits16) {
    return __uint_as_float(bits16 << 16);
}

// ---------------------------------------------------------------------------
// 1) xw = feats @ W via MFMA bf16. W staged in LDS fragment-major (32 KB).
//    All 16 A-tile float4 loads hoisted (one latency exposure per wave).
// ---------------------------------------------------------------------------
__global__ __launch_bounds__(256) void mfma_gemm_kernel(const float* __restrict__ feats,
                                                        const float* __restrict__ W,
                                                        u16* __restrict__ xwb) {
    __shared__ u16 wlds[32 * 64 * 8];   // 32 KB
    const int tid = threadIdx.x;
    for (int idx = tid; idx < 32 * 64; idx += 256) {
        const int f = idx >> 6, lane = idx & 63;
        const int kt = f >> 2, nt = f & 3;
        const int k0 = kt * 32 + (lane >> 4) * 8;
        const int n  = nt * 16 + (lane & 15);
        u32 buf[4];
#pragma unroll
        for (int jj = 0; jj < 4; ++jj) {
            u16 lo = f2bf_rne(W[(size_t)(k0 + 2 * jj) * EMB + n]);
            u16 hi = f2bf_rne(W[(size_t)(k0 + 2 * jj + 1) * EMB + n]);
            buf[jj] = (u32)lo | ((u32)hi << 16);
        }
        *(uint4*)&wlds[idx * 8] = *(uint4*)buf;
    }
    __syncthreads();

    const int wave = tid >> 6, lane = tid & 63;
    const int wid = blockIdx.x * 4 + wave;
    if (wid >= MWAVES) return;
    const int row0 = wid * 16;
    const int arow = row0 + (lane & 15);
    const int kbase = (lane >> 4) * 8;
    const float* fr = feats + (size_t)arow * IN_DIM + kbase;

    float4 av[16];
#pragma unroll
    for (int kt = 0; kt < 8; ++kt) {
        av[2 * kt]     = *(const float4*)(fr + kt * 32);
        av[2 * kt + 1] = *(const float4*)(fr + kt * 32 + 4);
    }

    f32x4 acc[4] = {};
    const u16* wl = &wlds[lane * 8];
#pragma unroll
    for (int kt = 0; kt < 8; ++kt) {
        float4 a0 = av[2 * kt], a1 = av[2 * kt + 1];
        u32 ab[4];
        ab[0] = (u32)f2bf_rne(a0.x) | ((u32)f2bf_rne(a0.y) << 16);
        ab[1] = (u32)f2bf_rne(a0.z) | ((u32)f2bf_rne(a0.w) << 16);
        ab[2] = (u32)f2bf_rne(a1.x) | ((u32)f2bf_rne(a1.y) << 16);
        ab[3] = (u32)f2bf_rne(a1.z) | ((u32)f2bf_rne(a1.w) << 16);
        bf16x8 afrag = *(bf16x8*)ab;
#pragma unroll
        for (int nt = 0; nt < 4; ++nt) {
            bf16x8 bfrag = *(const bf16x8*)&wl[(kt * 4 + nt) * 512];
            acc[nt] = __builtin_amdgcn_mfma_f32_16x16x32_bf16(afrag, bfrag, acc[nt], 0, 0, 0);
        }
    }
    const int rb = row0 + (lane >> 4) * 4;
    const int cb = lane & 15;
#pragma unroll
    for (int nt = 0; nt < 4; ++nt)
#pragma unroll
        for (int r = 0; r < 4; ++r)
            xwb[(size_t)(rb + r) * EMB + nt * 16 + cb] = f2bf_rne(acc[nt][r]);
}

// ---------------------------------------------------------------------------
// 2) passA: partition edges into NBUCK 128-row buckets (R6/R7-proven).
//    Entry packs (row:17 | col:17<<17 | val_bf16<<34).
// ---------------------------------------------------------------------------
__global__ __launch_bounds__(256) void passA_kernel(const int* __restrict__ erow,
                                                    const int* __restrict__ ecol,
                                                    const float* __restrict__ eval,
                                                    u32* __restrict__ gcursor,
                                                    u64* __restrict__ sorted) {
    __shared__ u64 stage[EPB];        // 32 KB
    __shared__ u32 hist[1024];
    __shared__ u32 offs[1024];
    __shared__ u32 cursor[1024];
    __shared__ u32 gbase[1024];
    __shared__ u32 partial[256];

    const int tid = threadIdx.x;
    const int e0 = blockIdx.x * EPB;
    const int total = min(EPB, N_EDGES - e0);

    for (int i = tid; i < 1024; i += 256) hist[i] = 0;
    __syncthreads();

    u64 ent[16];
    int eb[16];
#pragma unroll
    for (int j = 0; j < 16; ++j) {
        const int e = e0 + j * 256 + tid;
        if (e < N_EDGES) {
            const int r = erow[e];
            const int c = ecol[e];
            const u16 vb = f2bf_rne(eval[e]);
            ent[j] = (u64)(u32)r | ((u64)(u32)c << 17) | ((u64)vb << 34);
            eb[j] = r >> 7;
            atomicAdd(&hist[eb[j]], 1u);
        } else {
            eb[j] = -1;
        }
    }
    __syncthreads();

    u32 local[4], s = 0;
#pragma unroll
    for (int q = 0; q < 4; ++q) {
        local[q] = s;
        s += hist[4 * tid + q];
    }
    partial[tid] = s;
    __syncthreads();
    for (int off = 1; off < 256; off <<= 1) {
        u32 x = (tid >= off) ? partial[tid - off] : 0;
        __syncthreads();
        partial[tid] += x;
        __syncthreads();
    }
    const u32 base = partial[tid] - s;
#pragma unroll
    for (int q = 0; q < 4; ++q) {
        offs[4 * tid + q] = base + local[q];
        cursor[4 * tid + q] = base + local[q];
    }
    __syncthreads();

#pragma unroll
    for (int j = 0; j < 16; ++j) {
        if (eb[j] >= 0) {
            u32 pos = atomicAdd(&cursor[eb[j]], 1u);
            stage[pos] = ent[j];
        }
    }
    __syncthreads();

    for (int b = tid; b < 1024; b += 256) {
        const u32 cnt = cursor[b] - offs[b];
        gbase[b] = cnt ? atomicAdd(&gcursor[b], cnt) : 0;
    }
    __syncthreads();

    for (int i = tid; i < total; i += 256) {
        const u64 p = stage[i];
        const int b = (int)(p & 0x1FFFFu) >> 7;
        const u32 gpos = gbase[b] + ((u32)i - offs[b]);
        if (gpos < BSTRIDE) sorted[(size_t)b * BSTRIDE + gpos] = p;
    }
}

// ---------------------------------------------------------------------------
// 3) gather: one 1024-thread block (16 waves) per 128-row bucket.
//    Entries read ONCE, coalesced, into registers (<=5/thread); LDS row-sort;
//    each wave sweeps 8 rows with wave-uniform LDS reads + 8-wide unrolled
//    xw gathers. emb (bf16) overlays the bucket's own (dead) global region.
//    2 blocks/CU = 32 waves/CU (full occupancy); 12.5k waves total.
// ---------------------------------------------------------------------------
__global__ __launch_bounds__(1024, 8) void gather_kernel(const u16* __restrict__ xwb,
                                                         u64* __restrict__ sorted,
                                                         const u32* __restrict__ gcursor,
                                                         float* __restrict__ accumA) {
    __shared__ u64 stage[BSTRIDE];    // 36864 B
    __shared__ u32 rhist[BROWS], roff[BROWS], rcur[BROWS], sc[BROWS];
    __shared__ float part[16];
    const int tid = threadIdx.x, wave = tid >> 6, lane = tid & 63;
    const int b = blockIdx.x;
    u64* gbase = sorted + (size_t)b * BSTRIDE;
    const int cnt = min((int)gcursor[b], BSTRIDE);

    if (tid < BROWS) rhist[tid] = 0;
    __syncthreads();

    // coalesced one-shot read into registers + histogram from registers
    u64 ent[5];                       // ceil(4608/1024)
    int nloc = 0;
    for (int i = tid; i < cnt; i += 1024) {
        u64 p = gbase[i];
        ent[nloc++] = p;
        atomicAdd(&rhist[(int)(p & 127u)], 1u);
    }
    __syncthreads();

    // exclusive scan of 128 row counts (threads 0..127)
    if (tid < BROWS) sc[tid] = rhist[tid];
    __syncthreads();
    for (int off = 1; off < BROWS; off <<= 1) {
        u32 x = (tid < BROWS && tid >= off) ? sc[tid - off] : 0;
        __syncthreads();
        if (tid < BROWS) sc[tid] += x;
        __syncthreads();
    }
    if (tid < BROWS) {
        roff[tid] = sc[tid] - rhist[tid];
        rcur[tid] = sc[tid] - rhist[tid];
    }
    __syncthreads();

    // scatter from registers into row-grouped LDS stage
    for (int j = 0; j < nloc; ++j) {
        const u64 p = ent[j];
        const u32 pos = atomicAdd(&rcur[(int)(p & 127u)], 1u);
        stage[pos] = p;
    }
    __syncthreads();

    // sweep: wave handles rows wave*8 .. wave*8+7
    u16* embp = (u16*)gbase;          // entries dead (staged in LDS)
    float wd = 0.f;
    for (int rr = 0; rr < 8; ++rr) {
        const int r = wave * 8 + rr;
        const int s0 = roff[r], n = rhist[r];
        float acc = 0.f;
        int j = s0;
        const int e2 = s0 + n;
        for (; j + 7 < e2; j += 8) {
            u64 p0 = stage[j],     p1 = stage[j + 1], p2 = stage[j + 2], p3 = stage[j + 3];
            u64 p4 = stage[j + 4], p5 = stage[j + 5], p6 = stage[j + 6], p7 = stage[j + 7];
            float x0 = bf2f(xwb[(size_t)((p0 >> 17) & 0x1FFFFu) * EMB + lane]);
            float x1 = bf2f(xwb[(size_t)((p1 >> 17) & 0x1FFFFu) * EMB + lane]);
            float x2 = bf2f(xwb[(size_t)((p2 >> 17) & 0x1FFFFu) * EMB + lane]);
            float x3 = bf2f(xwb[(size_t)((p3 >> 17) & 0x1FFFFu) * EMB + lane]);
            float x4 = bf2f(xwb[(size_t)((p4 >> 17) & 0x1FFFFu) * EMB + lane]);
            float x5 = bf2f(xwb[(size_t)((p5 >> 17) & 0x1FFFFu) * EMB + lane]);
            float x6 = bf2f(xwb[(size_t)((p6 >> 17) & 0x1FFFFu) * EMB + lane]);
            float x7 = bf2f(xwb[(size_t)((p7 >> 17) & 0x1FFFFu) * EMB + lane]);
            acc += bf2f((u32)(p0 >> 34) & 0xFFFFu) * x0 + bf2f((u32)(p1 >> 34) & 0xFFFFu) * x1;
            acc += bf2f((u32)(p2 >> 34) & 0xFFFFu) * x2 + bf2f((u32)(p3 >> 34) & 0xFFFFu) * x3;
            acc += bf2f((u32)(p4 >> 34) & 0xFFFFu) * x4 + bf2f((u32)(p5 >> 34) & 0xFFFFu) * x5;
            acc += bf2f((u32)(p6 >> 34) & 0xFFFFu) * x6 + bf2f((u32)(p7 >> 34) & 0xFFFFu) * x7;
        }
        for (; j < e2; ++j) {
            u64 p = stage[j];
            acc += bf2f((u32)(p >> 34) & 0xFFFFu) * bf2f(xwb[(size_t)((p >> 17) & 0x1FFFFu) * EMB + lane]);
        }
        float x = tanhf(acc);
        float sq = wave_sum(x * x);
        if (b * BROWS + r < N_NODES)
            embp[r * EMB + lane] = f2bf_rne(x * rsqrtf(fmaxf(sq, 1e-12f)));
        wd += sq / fmaxf(sq, 1e-12f);   // 0 for empty rows
    }
    if (lane == 0) part[wave] = wd;
    __syncthreads();
    if (tid == 0) {
        float v = 0.f;
#pragma unroll
        for (int w = 0; w < 16; ++w) v += part[w];
        unsafeAtomicAdd(&accumA[b & 255], v);
    }
}

// ---------------------------------------------------------------------------
// 4) BPR: pure emb lookup. One wave per sample.
// ---------------------------------------------------------------------------
__device__ __forceinline__ float emb_ld(const u64* __restrict__ sorted, int row, int lane) {
    const u16* rp = (const u16*)(sorted + (size_t)(row >> 7) * BSTRIDE) + (row & 127) * EMB;
    return bf2f(rp[lane]);
}

__global__ __launch_bounds__(256) void bpr_kernel(const u64* __restrict__ sorted,
                                                  const int* __restrict__ idx1,
                                                  const int* __restrict__ idx2,
                                                  const int* __restrict__ nidx,
                                                  float* __restrict__ accumB) {
    const int wave = threadIdx.x >> 6, lane = threadIdx.x & 63;
    const int i = blockIdx.x * 4 + wave;
    float o1 = emb_ld(sorted, idx1[i], lane);
    float o2 = emb_ld(sorted, idx2[i], lane);
    float on = emb_ld(sorted, nidx[i], lane);
    float yui = wave_sum(o1 * o2);
    float yuj = wave_sum(o1 * on);
    if (lane == 0) {
        float x = yui - yuj;
        float li = (x > 0.f) ? log1pf(expf(-x)) : (-x + log1pf(expf(x)));
        unsafeAtomicAdd(&accumB[i & 255], li);
    }
}

// ---------------------------------------------------------------------------
// 5) finalize
// ---------------------------------------------------------------------------
__global__ __launch_bounds__(64) void finalize_kernel(const float* __restrict__ accumA,
                                                      const float* __restrict__ accumB,
                                                      float* __restrict__ out) {
    const int t = threadIdx.x;
    float wd = 0.f, bp = 0.f;
#pragma unroll
    for (int k = 0; k < 4; ++k) {
        wd += accumA[t + 64 * k];
        bp += accumB[t + 64 * k];
    }
    wd = wave_sum(wd);
    bp = wave_sum(bp);
    if (t == 0) out[0] = (bp + 1e-4f * 0.5f * wd) / (float)BATCH;
}

extern "C" void kernel_launch(void* const* d_in, const int* in_sizes, int n_in,
                              void* d_out, int out_size, void* d_ws, size_t ws_size,
                              hipStream_t stream) {
    const float* feats = (const float*)d_in[0];
    const float* W     = (const float*)d_in[1];
    const int*   erow  = (const int*)d_in[2];
    const int*   ecol  = (const int*)d_in[3];
    const float* eval  = (const float*)d_in[4];
    const int*   idx1  = (const int*)d_in[5];
    const int*   idx2  = (const int*)d_in[6];
    const int*   nidx  = (const int*)d_in[7];
    float* out = (float*)d_out;

    // workspace layout (~41.7 MB)
    u16*   xwb     = (u16*)d_ws;                               // 12.8 MB
    u64*   sorted  = (u64*)(xwb + (size_t)N_NODES * EMB);      // 782*4608*8 = 28.8 MB
    u32*   gcursor = (u32*)(sorted + (size_t)NBUCK * BSTRIDE); // 1024
    float* accumA  = (float*)(gcursor + 1024);                 // 256
    float* accumB  = accumA + 256;                             // 256

    hipMemsetAsync(gcursor, 0, (1024 + 512) * sizeof(u32), stream);

    mfma_gemm_kernel<<<(MWAVES + 3) / 4, 256, 0, stream>>>(feats, W, xwb);
    passA_kernel<<<(N_EDGES + EPB - 1) / EPB, 256, 0, stream>>>(erow, ecol, eval, gcursor, sorted);
    gather_kernel<<<NBUCK, 1024, 0, stream>>>(xwb, sorted, gcursor, accumA);
    bpr_kernel<<<BATCH / 4, 256, 0, stream>>>(sorted, idx1, idx2, nidx, accumB);
    finalize_kernel<<<1, 64, 0, stream>>>(accumA, accumB, out);
}